// Round 8
// baseline (593.111 us; speedup 1.0000x reference)
//
#include <hip/hip_runtime.h>
#include <math.h>

#define D 512
#define AS1 __attribute__((address_space(1)))
#define AS3 __attribute__((address_space(3)))

typedef _Float16 f16x8 __attribute__((ext_vector_type(8)));
typedef float f32x4 __attribute__((ext_vector_type(4)));

// ---------------- Transpose: zTb[g][d][kk_swz] = fp16(h[g*32+k][d]) ----------------
__global__ __launch_bounds__(256) void transpose_kernel(
    const float* __restrict__ h, _Float16* __restrict__ zTb, int N)
{
    __shared__ float tile[64][65];
    const int t0 = blockIdx.x * 64;
    const int d0 = blockIdx.y * 64;
    const int tid = threadIdx.x;
    const int r0 = tid >> 4;
    const int c0 = (tid & 15) * 4;
    #pragma unroll
    for (int k = 0; k < 4; k++) {
        int r = r0 + k * 16;
        float4 v = *(const float4*)(h + (size_t)(t0 + r) * D + d0 + c0);
        tile[r][c0] = v.x; tile[r][c0+1] = v.y; tile[r][c0+2] = v.z; tile[r][c0+3] = v.w;
    }
    __syncthreads();
    const int g = (t0 >> 5) + (c0 >> 5);
    const int kk = c0 & 31;
    const int kg = kk >> 3;
    const int sub = kk & 7;
    #pragma unroll
    for (int k = 0; k < 4; k++) {
        int dd = d0 + r0 + k * 16;
        int kks = ((kg + (dd >> 1)) & 3) * 8 + sub;
        union { _Float16 hh[4]; uint2 u2; } pk;
        #pragma unroll
        for (int i = 0; i < 4; i++) pk.hh[i] = (_Float16)tile[c0 + i][r0 + k * 16];
        *(uint2*)(zTb + (size_t)g * 16384 + dd * 32 + kks) = pk.u2;
    }
}

// ---------------- Linear via fp16 MFMA: x16 = fp16(h @ W^T + b) ----------------
__global__ __launch_bounds__(256) void linear_mfma(
    const float* __restrict__ h, const float* __restrict__ W,
    const float* __restrict__ bias, _Float16* __restrict__ x16, int N)
{
    __shared__ _Float16 sA[128 * 72];
    __shared__ _Float16 sB[128 * 72];
    const int tid  = threadIdx.x;
    const int m0 = blockIdx.x * 128;
    const int n0 = blockIdx.y * 128;
    const int wave = tid >> 6, lane = tid & 63;
    const int l15 = lane & 15, quad = lane >> 4;
    const int wm = (wave >> 1) * 64, wn = (wave & 1) * 64;

    f32x4 acc[4][4];
    #pragma unroll
    for (int mi = 0; mi < 4; mi++)
        #pragma unroll
        for (int ni = 0; ni < 4; ni++) acc[mi][ni] = (f32x4){0.f,0.f,0.f,0.f};

    for (int k0 = 0; k0 < D; k0 += 64) {
        __syncthreads();
        #pragma unroll
        for (int i = 0; i < 8; i++) {
            int idx = tid + 256 * i;
            int row = idx >> 4;
            int c4  = (idx & 15) * 4;
            float4 va = *(const float4*)(h + (size_t)(m0 + row) * D + k0 + c4);
            float4 vb = *(const float4*)(W + (size_t)(n0 + row) * D + k0 + c4);
            union { _Float16 hh[4]; uint2 u2; } pa, pb;
            pa.hh[0] = (_Float16)va.x; pa.hh[1] = (_Float16)va.y;
            pa.hh[2] = (_Float16)va.z; pa.hh[3] = (_Float16)va.w;
            pb.hh[0] = (_Float16)vb.x; pb.hh[1] = (_Float16)vb.y;
            pb.hh[2] = (_Float16)vb.z; pb.hh[3] = (_Float16)vb.w;
            *(uint2*)(sA + row * 72 + c4) = pa.u2;
            *(uint2*)(sB + row * 72 + c4) = pb.u2;
        }
        __syncthreads();
        #pragma unroll
        for (int kc = 0; kc < 2; kc++) {
            f16x8 a[4], b[4];
            #pragma unroll
            for (int mi = 0; mi < 4; mi++)
                a[mi] = *(const f16x8*)(sA + (wm + mi*16 + l15)*72 + kc*32 + quad*8);
            #pragma unroll
            for (int ni = 0; ni < 4; ni++)
                b[ni] = *(const f16x8*)(sB + (wn + ni*16 + l15)*72 + kc*32 + quad*8);
            #pragma unroll
            for (int mi = 0; mi < 4; mi++)
                #pragma unroll
                for (int ni = 0; ni < 4; ni++)
                    acc[mi][ni] = __builtin_amdgcn_mfma_f32_16x16x32_f16(a[mi], b[ni], acc[mi][ni], 0, 0, 0);
        }
    }
    float bv[4];
    #pragma unroll
    for (int ni = 0; ni < 4; ni++) bv[ni] = bias[n0 + wn + ni*16 + l15];
    #pragma unroll
    for (int mi = 0; mi < 4; mi++)
        #pragma unroll
        for (int ni = 0; ni < 4; ni++)
            #pragma unroll
            for (int r = 0; r < 4; r++) {
                int row = m0 + wm + mi*16 + quad*4 + r;
                x16[(size_t)row * D + n0 + wn + ni*16 + l15] = (_Float16)(acc[mi][ni][r] + bv[ni]);
            }
}

// ---------------- Flash attention v16: dim-split, duplicated softmax (fixed) ----
// Wave (g,h) owns q-group g (32 queries) x dim-half h (256 dims).
//  scores: partial over own 256d (B-frag shared across 2 q-subtiles); both
//  subtiles' partials exchanged via sx [32][32] f32 (bijective, 2-way banks);
//  each wave merges partner partials and runs the FULL 32q softmax itself
//  (duplicated VALU, zero cross-wave softmax/P dependency). PV: O = 32q x own
//  256d, each z-frag read once feeds both subtiles.
// ybuf unpadded (stride 512) with XOR-granule swizzle (src granule lane^(r&7),
// read granule gi^(l15&7)) -> 2-way banks, saves the pad -> LDS exactly 81,920
// = 2 blocks/CU (8 waves, 2/SIMD).
// Barriers (all with lgkmcnt(0) -- closes in-flight ds_read races):
//  BAR1: lgkm only (sx visible; ybuf reads done)
//  BAR2: vmcnt(8)+lgkm (z landed, y(kb+1) still flying; sxr reads done ->
//        partner P-overlay safe)
//  BAR3: vmcnt(0)+lgkm (y landed; zbuf reads done -> next z-DMA safe)
__global__ __launch_bounds__(256, 2) void attn16_kernel(
    const float* __restrict__ h, const _Float16* __restrict__ x16,
    const _Float16* __restrict__ zTb, const int* __restrict__ lens,
    float* __restrict__ out, int N, int B)
{
    // ybuf [32][512] f16 swz @ 0      32,768
    // zbuf [512][32] f16 swz @ 32768  32,768
    // sx   4 x [32][32] f32  @ 65536  16,384   (P overlays own slot: 2,560 B)
    __shared__ __align__(16) unsigned char smem[81920];
    _Float16* ybuf = (_Float16*)smem;
    _Float16* zbuf = (_Float16*)(smem + 32768);

    const int is64 = (lens[1] == 0 && lens[3] == 0) ? 1 : 0;

    int seg = -1, tile = 0;
    if (B == 16) {
        const int xcd = blockIdx.x & 7;
        const int idx = blockIdx.x >> 3;
        const int sL = 15 - xcd, sS = xcd;
        const int LL = is64 ? lens[2 * sL] : lens[sL];
        const int LS = is64 ? lens[2 * sS] : lens[sS];
        const int ntL = (LL + 63) >> 6;
        const int ntS = (LS + 63) >> 6;
        if (idx < ntL)            { seg = sL; tile = idx; }
        else if (idx < ntL + ntS) { seg = sS; tile = idx - ntL; }
        else return;
    } else {
        int blk = blockIdx.x;
        int acc = 0;
        for (int t = 0; t < B; t++) {
            int s = B - 1 - t;
            int Ls = is64 ? lens[2 * s] : lens[s];
            int nt = (Ls + 63) >> 6;
            if (seg < 0 && blk < acc + nt) { seg = s; tile = blk - acc; }
            acc += nt;
        }
        if (seg < 0) return;
    }
    int off = 0;
    for (int t = 0; t < seg; t++) off += is64 ? lens[2 * t] : lens[t];
    const int len = is64 ? lens[2 * seg] : lens[seg];

    const int tid  = threadIdx.x;
    const int wv   = tid >> 6;
    const int g    = wv >> 1;        // q-group (32 queries)
    const int hh   = wv & 1;         // dim half
    const int lane = tid & 63;
    const int l15  = lane & 15;
    const int quad = lane >> 4;
    const int zcol = ((quad + (l15 >> 1)) & 3) * 8;
    const int nkb  = (len + 31) >> 5;

    float* sxw = (float*)(smem + 65536 + wv * 4096);
    const float* sxr = (const float*)(smem + 65536 + (wv ^ 1) * 4096);
    _Float16* Pp = (_Float16*)(smem + 65536 + wv * 4096);
    // sx lane mapping: row = j*2 + (quad>>1), col = (quad&1)*16 + l15  (bijective)
    const int sxo = (quad >> 1) * 32 + (quad & 1) * 16 + l15;

    // Q fragments: 2 q-subtiles x 8 chunks over dims [hh*256, hh*256+256)
    f16x8 Qf[2][8];
    #pragma unroll
    for (int ts = 0; ts < 2; ts++) {
        int qr = off + tile * 64 + g * 32 + ts * 16 + l15;
        if (qr > N - 1) qr = N - 1;
        const float* hr = h + (size_t)qr * D + hh * 256;
        #pragma unroll
        for (int cc = 0; cc < 8; cc++) {
            float4 u = *(const float4*)(hr + cc * 32 + quad * 8);
            float4 v = *(const float4*)(hr + cc * 32 + quad * 8 + 4);
            f16x8 q;
            q[0] = (_Float16)u.x; q[1] = (_Float16)u.y; q[2] = (_Float16)u.z; q[3] = (_Float16)u.w;
            q[4] = (_Float16)v.x; q[5] = (_Float16)v.y; q[6] = (_Float16)v.z; q[7] = (_Float16)v.w;
            Qf[ts][cc] = q;
        }
    }

    f32x4 O[2][16];
    #pragma unroll
    for (int ts = 0; ts < 2; ts++)
        #pragma unroll
        for (int f = 0; f < 16; f++) O[ts][f] = (f32x4){0.f,0.f,0.f,0.f};
    float mR[2][4], lR[2][4];
    #pragma unroll
    for (int ts = 0; ts < 2; ts++)
        #pragma unroll
        for (int r = 0; r < 4; r++) { mR[ts][r] = -1e30f; lR[ts][r] = 0.f; }

    // ---- prologue: stage y(0), swizzled source granule lane^(r&7) ----
    #pragma unroll
    for (int i = 0; i < 8; i++) {
        int r = wv * 8 + i;
        int gr = off + r; if (gr > N - 1) gr = N - 1;
        const _Float16* gsrc = x16 + (size_t)gr * D + (lane ^ (r & 7)) * 8;
        __builtin_amdgcn_global_load_lds((const AS1 unsigned int*)gsrc,
                                         (AS3 unsigned int*)(ybuf + r * 512), 16, 0, 0);
    }
    asm volatile("s_waitcnt vmcnt(0) lgkmcnt(0)" ::: "memory");
    __builtin_amdgcn_s_barrier();

    for (int kb = 0; kb < nkb; kb++) {
        // ---- top: issue z(kb) (zbuf free since BAR3 of kb-1) ----
        {
            const _Float16* zsrc = zTb + (size_t)((off + kb * 32) >> 5) * 16384;
            #pragma unroll
            for (int i = 0; i < 8; i++) {
                int co = (wv * 8 + i) * 512 + lane * 8;
                __builtin_amdgcn_global_load_lds((const AS1 unsigned int*)(zsrc + co),
                                                 (AS3 unsigned int*)(zbuf + co), 16, 0, 0);
            }
        }

        // ---- scores partial over own 256 dims (swizzled ybuf reads) ----
        f32x4 s[2][2];
        #pragma unroll
        for (int ts = 0; ts < 2; ts++)
            #pragma unroll
            for (int kt = 0; kt < 2; kt++) s[ts][kt] = (f32x4){0.f,0.f,0.f,0.f};
        __builtin_amdgcn_s_setprio(1);
        #pragma unroll
        for (int cc = 0; cc < 8; cc++) {
            int p = (hh * 32 + cc * 4 + quad) ^ (l15 & 7);   // swizzled granule
            f16x8 b0 = *(const f16x8*)(ybuf + l15 * 512 + p * 8);
            f16x8 b1 = *(const f16x8*)(ybuf + (16 + l15) * 512 + p * 8);
            s[0][0] = __builtin_amdgcn_mfma_f32_16x16x32_f16(Qf[0][cc], b0, s[0][0], 0, 0, 0);
            s[1][0] = __builtin_amdgcn_mfma_f32_16x16x32_f16(Qf[1][cc], b0, s[1][0], 0, 0, 0);
            s[0][1] = __builtin_amdgcn_mfma_f32_16x16x32_f16(Qf[0][cc], b1, s[0][1], 0, 0, 0);
            s[1][1] = __builtin_amdgcn_mfma_f32_16x16x32_f16(Qf[1][cc], b1, s[1][1], 0, 0, 0);
        }
        __builtin_amdgcn_s_setprio(0);

        // ---- write own partials (both subtiles), sx[32][32] bijective ----
        #pragma unroll
        for (int ts = 0; ts < 2; ts++)
            #pragma unroll
            for (int kt = 0; kt < 2; kt++)
                #pragma unroll
                for (int r = 0; r < 4; r++)
                    sxw[((ts * 2 + kt) * 4 + r) * 64 + sxo] = s[ts][kt][r];

        asm volatile("s_waitcnt lgkmcnt(0)" ::: "memory");
        __builtin_amdgcn_s_barrier();          // BAR1: sx visible; ybuf free

        // ---- issue y(kb+1), swizzled source ----
        if (kb + 1 < nkb) {
            const int jn = (kb + 1) * 32;
            #pragma unroll
            for (int i = 0; i < 8; i++) {
                int r = wv * 8 + i;
                int gr = off + jn + r; if (gr > N - 1) gr = N - 1;
                const _Float16* gsrc = x16 + (size_t)gr * D + (lane ^ (r & 7)) * 8;
                __builtin_amdgcn_global_load_lds((const AS1 unsigned int*)gsrc,
                                                 (AS3 unsigned int*)(ybuf + r * 512), 16, 0, 0);
            }
        }

        // ---- merge partner partials + mask ----
        #pragma unroll
        for (int ts = 0; ts < 2; ts++)
            #pragma unroll
            for (int kt = 0; kt < 2; kt++)
                #pragma unroll
                for (int r = 0; r < 4; r++)
                    s[ts][kt][r] += sxr[((ts * 2 + kt) * 4 + r) * 64 + sxo];
        const int kk0 = kb * 32 + l15, kk1 = kb * 32 + 16 + l15;
        #pragma unroll
        for (int ts = 0; ts < 2; ts++)
            #pragma unroll
            for (int r = 0; r < 4; r++) {
                if (kk0 >= len) s[ts][0][r] = -1e30f;
                if (kk1 >= len) s[ts][1][r] = -1e30f;
            }

        // BAR2: z(kb) landed (counted: y-loads may stay in flight); sxr reads
        // complete -> partner's P overlay safe.
        if (kb + 1 < nkb) {
            asm volatile("s_waitcnt vmcnt(8) lgkmcnt(0)" ::: "memory");
        } else {
            asm volatile("s_waitcnt vmcnt(0) lgkmcnt(0)" ::: "memory");
        }
        __builtin_amdgcn_s_barrier();

        // ---- full 32q softmax (wave-private, duplicated across pair, defer-max) ----
        float al[2][4];
        bool need = false;
        #pragma unroll
        for (int ts = 0; ts < 2; ts++) {
            #pragma unroll
            for (int r = 0; r < 4; r++) {
                float t = fmaxf(s[ts][0][r], s[ts][1][r]);
                t = fmaxf(t, __shfl_xor(t, 1, 16));
                t = fmaxf(t, __shfl_xor(t, 2, 16));
                t = fmaxf(t, __shfl_xor(t, 4, 16));
                t = fmaxf(t, __shfl_xor(t, 8, 16));
                bool upd = (t > mR[ts][r] + 8.0f);
                float mn = upd ? t : mR[ts][r];
                al[ts][r] = upd ? __expf(mR[ts][r] - mn) : 1.0f;
                mR[ts][r] = mn;
                float e0 = __expf(s[ts][0][r] - mn);
                float e1 = __expf(s[ts][1][r] - mn);
                float ps = e0 + e1;
                ps += __shfl_xor(ps, 1, 16);
                ps += __shfl_xor(ps, 2, 16);
                ps += __shfl_xor(ps, 4, 16);
                ps += __shfl_xor(ps, 8, 16);
                lR[ts][r] = lR[ts][r] * al[ts][r] + ps;
                Pp[ts * 640 + (quad * 4 + r) * 40 + l15]      = (_Float16)e0;
                Pp[ts * 640 + (quad * 4 + r) * 40 + 16 + l15] = (_Float16)e1;
                need |= upd;
            }
        }

        // ---- rescale O (rare), read P back (same-wave) ----
        if (__ballot(need)) {
            f32x4 av0, av1;
            #pragma unroll
            for (int r = 0; r < 4; r++) { av0[r] = al[0][r]; av1[r] = al[1][r]; }
            #pragma unroll
            for (int f = 0; f < 16; f++) { O[0][f] *= av0; O[1][f] *= av1; }
        }
        f16x8 pf0 = *(const f16x8*)(Pp + l15 * 40 + quad * 8);
        f16x8 pf1 = *(const f16x8*)(Pp + 640 + l15 * 40 + quad * 8);

        // ---- PV over own dim half: 1 z-read feeds both subtiles ----
        __builtin_amdgcn_s_setprio(1);
        #pragma unroll
        for (int f = 0; f < 16; f++) {
            f16x8 zf = *(const f16x8*)(zbuf + ((hh * 16 + f) * 16 + l15) * 32 + zcol);
            O[0][f] = __builtin_amdgcn_mfma_f32_16x16x32_f16(pf0, zf, O[0][f], 0, 0, 0);
            O[1][f] = __builtin_amdgcn_mfma_f32_16x16x32_f16(pf1, zf, O[1][f], 0, 0, 0);
        }
        __builtin_amdgcn_s_setprio(0);

        // BAR3: y(kb+1) landed; zbuf reads complete -> next z-DMA safe.
        asm volatile("s_waitcnt vmcnt(0) lgkmcnt(0)" ::: "memory");
        __builtin_amdgcn_s_barrier();
    }

    // ---- epilogue: wave writes its 32q x own 256d ----
    #pragma unroll
    for (int ts = 0; ts < 2; ts++) {
        #pragma unroll
        for (int r = 0; r < 4; r++) {
            int qloc = tile * 64 + g * 32 + ts * 16 + quad * 4 + r;
            if (qloc < len) {
                float inv = 1.0f / lR[ts][r];
                float* orow = out + (size_t)(off + qloc) * D + hh * 256 + l15;
                #pragma unroll
                for (int f = 0; f < 16; f++) orow[f * 16] = O[ts][f][r] * inv;
            }
        }
    }
}

extern "C" void kernel_launch(void* const* d_in, const int* in_sizes, int n_in,
                              void* d_out, int out_size, void* d_ws, size_t ws_size,
                              hipStream_t stream) {
    const float* h    = (const float*)d_in[0];
    const float* W    = (const float*)d_in[1];
    const float* bias = (const float*)d_in[2];
    const int*   lens = (const int*)d_in[3];
    float* outp = (float*)d_out;

    const int N = in_sizes[0] / D;                 // 24064
    int B = in_sizes[3]; if (B > 16) B = 16;

    _Float16* x16 = (_Float16*)d_ws;                                  // N*D fp16
    _Float16* zTb = (_Float16*)((char*)d_ws + (size_t)N * D * 2);     // blocked+swizzled z^T

    dim3 g2(N / 64, D / 64);
    transpose_kernel<<<g2, 256, 0, stream>>>(h, zTb, N);

    dim3 g1(N / 128, D / 128);
    linear_mfma<<<g1, 256, 0, stream>>>(h, W, bias, x16, N);

    const int nblk = N / 64 + B;
    attn16_kernel<<<nblk, 256, 0, stream>>>(h, x16, zTb, lens, outp, N, B);
}